// Round 10
// baseline (107.568 us; speedup 1.0000x reference)
//
#include <hip/hip_runtime.h>
#include <hip/hip_bf16.h>

// ChebyKANLinear: y[b,j] = sum_i sum_k T_k(tanh(x[b,i])) * C[i,j,k]
// GEMM: M=16384, N=512, K=4608 (kflat = k*512 + i).
// v9: barrier-free (no LDS), B register-double-buffered from L2-resident W2.
//     NEW: (a) k=0 term folded into a precomputed column constant S0[j]
//     (acc init) -> 8 even ksteps/ic, 11% less MFMA; (b) wave tile 64x64,
//     ~240 unified regs -> 2 waves/SIMD so two waves' MFMA/VALU overlap
//     (m114). f32 recurrence, bf16 MFMA operands (proven 2.44e-4).

typedef __bf16 bf16x8 __attribute__((ext_vector_type(8)));
typedef float  f32x4  __attribute__((ext_vector_type(4)));

#define DIM  512
#define KDEG 9
#define NIC  16
#define SLAB (4 * DIM * 8)   // 16384 bf16 per (k,ic) slab

// ---- pack: C[i][j][k] -> W2[(k*16+ic)][s][j][e] (bf16), i = ic*32 + s*8 + e ----
__global__ void pack_w_kernel(const float* __restrict__ coeffs,
                              __bf16* __restrict__ W2) {
    int t  = blockIdx.x * blockDim.x + threadIdx.x;   // 32768 threads
    int j  = t & (DIM - 1);
    int s  = (t >> 9) & 3;
    int ic = t >> 11;

    bf16x8 v[KDEG];
#pragma unroll
    for (int e = 0; e < 8; ++e) {
        int i = ic * 32 + s * 8 + e;
        const float* src = coeffs + ((size_t)i * DIM + j) * KDEG;
#pragma unroll
        for (int k = 0; k < KDEG; ++k)
            v[k][e] = (__bf16)src[k];
    }
#pragma unroll
    for (int k = 0; k < KDEG; ++k) {
        size_t off = (size_t)(k * 16 + ic) * SLAB + ((size_t)s * DIM + j) * 8;
        *reinterpret_cast<bf16x8*>(W2 + off) = v[k];
    }
}

// ---- S0[j] = sum_i C[i][j][0] (f32), stored into W2's unused k=0 slab ----
__global__ void s0_kernel(const float* __restrict__ coeffs,
                          float* __restrict__ S0) {
    const int j    = blockIdx.x;      // 512 blocks
    const int lane = threadIdx.x;     // 64
    float s = 0.0f;
#pragma unroll
    for (int i = lane; i < DIM; i += 64)
        s += coeffs[((size_t)i * DIM + j) * KDEG];
#pragma unroll
    for (int off = 32; off > 0; off >>= 1)
        s += __shfl_down(s, off, 64);
    if (lane == 0) S0[j] = s;
}

// ---------------- fused Chebyshev-basis + MFMA GEMM, barrier-free ---------------
__global__ __launch_bounds__(256, 2) void cheby_gemm_kernel(
    const float* __restrict__ x,
    const __bf16* __restrict__ W2,
    float* __restrict__ out)
{
    const int tid  = threadIdx.x;
    const int lane = tid & 63;
    const int wid  = tid >> 6;      // 0..3
    const int wr   = wid >> 1;      // 0..1  m-half (64 rows)
    const int wc   = wid & 1;       // 0..1  n-half (64 cols)
    const int l15  = lane & 15;
    const int l4   = lane >> 4;     // 0..3
    const int bm   = blockIdx.y * 128;
    const int bn   = blockIdx.x * 128;

    // B lane base: granule (l4*DIM + bn + wc*64 + nf*16 + l15), 16B each
    const __bf16* wbase = W2 + ((size_t)l4 * DIM + bn + wc * 64 + l15) * 8;

    // x rows: bm + wr*64 + mf*16 + l15; lane's 8 i's at slot l4
    const float* xr = x + (size_t)(bm + wr * 64 + l15) * DIM + l4 * 8;

    // acc init from S0 (the k=0 term): every row of col gets S0[col]
    const float* S0 = (const float*)W2;   // first 2KB of unused k=0 slab
    f32x4 acc[4][4];
#pragma unroll
    for (int nf = 0; nf < 4; ++nf) {
        float s0v = S0[bn + wc * 64 + nf * 16 + l15];
#pragma unroll
        for (int mf = 0; mf < 4; ++mf)
#pragma unroll
            for (int r = 0; r < 4; ++r)
                acc[mf][nf][r] = s0v;
    }

    // B register buffers: 2 sets (8 even ksteps/ic -> parity-safe across ic).
    // prologue: (k=1, ic=0) into set 0.
    bf16x8 bq[2][4];
#pragma unroll
    for (int nf = 0; nf < 4; ++nf)
        bq[0][nf] = *reinterpret_cast<const bf16x8*>(
            wbase + (size_t)16 * SLAB + nf * 128);

    for (int ic = 0; ic < NIC; ++ic) {
        // ---- basis init (f32): t = tanh(x) = 1 - 2/(exp2(2*log2e*x)+1) ----
        float t2[4][8], Tk[4][8], Tm[4][8];
#pragma unroll
        for (int mf = 0; mf < 4; ++mf) {
            f32x4 xa = *reinterpret_cast<const f32x4*>(xr + mf * 16 * DIM + ic * 32);
            f32x4 xb = *reinterpret_cast<const f32x4*>(xr + mf * 16 * DIM + ic * 32 + 4);
#pragma unroll
            for (int e = 0; e < 8; ++e) {
                float xv = (e < 4) ? xa[e] : xb[e - 4];
                float p  = __builtin_amdgcn_exp2f(xv * 2.8853900817779268f);
                float t  = 1.0f - 2.0f * __builtin_amdgcn_rcpf(p + 1.0f);
                Tk[mf][e] = t;          // T_1
                t2[mf][e] = t + t;
                Tm[mf][e] = 1.0f;       // T_0
            }
        }

#pragma unroll
        for (int k = 1; k < KDEG; ++k) {
            const int cs = (k - 1) & 1;     // consume set; parity-safe (8 steps/ic)
            // prefetch next kstep (depth 1) into the other set
            if ((k < KDEG - 1) || (ic + 1 < NIC)) {
                const int nk  = (k < KDEG - 1) ? k + 1 : 1;
                const int nic = (k < KDEG - 1) ? ic : ic + 1;
                const __bf16* np = wbase + (size_t)(nk * 16 + nic) * SLAB;
#pragma unroll
                for (int nf = 0; nf < 4; ++nf)
                    bq[cs ^ 1][nf] = *reinterpret_cast<const bf16x8*>(np + nf * 128);
            }

            // A fragments (f32 -> bf16 operand rounding only)
            bf16x8 af[4];
#pragma unroll
            for (int mf = 0; mf < 4; ++mf)
#pragma unroll
                for (int e = 0; e < 8; ++e)
                    af[mf][e] = (__bf16)Tk[mf][e];

            // 16 MFMA (independent accumulators)
#pragma unroll
            for (int nf = 0; nf < 4; ++nf)
#pragma unroll
                for (int mf = 0; mf < 4; ++mf)
                    acc[mf][nf] = __builtin_amdgcn_mfma_f32_16x16x32_bf16(
                        af[mf], bq[cs][nf], acc[mf][nf], 0, 0, 0);

            // advance recurrence in f32: Tn = 2t*Tk - Tm
            if (k < KDEG - 1) {
#pragma unroll
                for (int mf = 0; mf < 4; ++mf)
#pragma unroll
                    for (int e = 0; e < 8; ++e) {
                        float Tn = __builtin_fmaf(t2[mf][e], Tk[mf][e], -Tm[mf][e]);
                        Tm[mf][e] = Tk[mf][e];
                        Tk[mf][e] = Tn;
                    }
            }
        }
    }

    // ---- epilogue: C/D layout col=lane&15, row=(lane>>4)*4+r ----
#pragma unroll
    for (int mf = 0; mf < 4; ++mf)
#pragma unroll
        for (int r = 0; r < 4; ++r) {
            const int row = bm + wr * 64 + mf * 16 + l4 * 4 + r;
            float* orow = out + (size_t)row * DIM + bn + wc * 64 + l15;
#pragma unroll
            for (int nf = 0; nf < 4; ++nf)
                orow[nf * 16] = acc[mf][nf][r];
        }
}

extern "C" void kernel_launch(void* const* d_in, const int* in_sizes, int n_in,
                              void* d_out, int out_size, void* d_ws, size_t ws_size,
                              hipStream_t stream) {
    const float* x      = (const float*)d_in[0];   // (16384, 512)
    const float* coeffs = (const float*)d_in[1];   // (512, 512, 9)
    float* out          = (float*)d_out;           // (16384, 512)
    __bf16* W2          = (__bf16*)d_ws;           // 144*16384 bf16 = 4.7MB

    pack_w_kernel<<<(DIM * 64) / 256, 256, 0, stream>>>(coeffs, W2);
    // S0 into the (unused by GEMM) k=0 slab region of W2; stream-ordered after pack
    s0_kernel<<<DIM, 64, 0, stream>>>(coeffs, (float*)W2);

    // grid = (N/128, M/128) = (4, 128) = 512 blocks = 2/CU = 2 waves/SIMD
    cheby_gemm_kernel<<<dim3(4, 128), 256, 0, stream>>>(x, W2, out);
}